// Round 1
// baseline (714.105 us; speedup 1.0000x reference)
//
#include <hip/hip_runtime.h>
#include <hip/hip_bf16.h>
#include <math.h>

typedef __hip_bfloat16 bf16;
typedef __attribute__((ext_vector_type(4))) float f32x4;
typedef __attribute__((ext_vector_type(8))) short s16x8;

#define NB 8192
#define KP 1120   // padded K: 1089 -> 35*32
#define NP 1152   // padded N: 1089 -> 9*128

// ---------------- BatchNorm stats (fold into layer-1) ----------------
__global__ void stats_partial(const float* __restrict__ x, int F,
                              float* __restrict__ sum, float* __restrict__ sumsq) {
    int fl = threadIdx.x & 63;
    int rg = threadIdx.x >> 6;               // 0..3
    int f = blockIdx.x * 64 + fl;
    int rc = blockIdx.y;                     // 32 row chunks of 256
    float s = 0.f, s2 = 0.f;
    if (f < F) {
        int rend = rc * 256 + 256;
        for (int r = rc * 256 + rg; r < rend; r += 4) {
            float v = x[(size_t)r * F + f];
            s += v; s2 += v * v;
        }
    }
    __shared__ float l1[4][64], l2[4][64];
    l1[rg][fl] = s; l2[rg][fl] = s2;
    __syncthreads();
    if (rg == 0 && f < F) {
        float S  = l1[0][fl] + l1[1][fl] + l1[2][fl] + l1[3][fl];
        float S2 = l2[0][fl] + l2[1][fl] + l2[2][fl] + l2[3][fl];
        atomicAdd(&sum[f], S);
        atomicAdd(&sumsq[f], S2);
    }
}

__global__ void stats_finalize(const float* __restrict__ sum, const float* __restrict__ sumsq,
                               const float* __restrict__ gamma, const float* __restrict__ beta,
                               int F, float* __restrict__ a_out, float* __restrict__ c_out) {
    int f = blockIdx.x * 256 + threadIdx.x;
    if (f >= F) return;
    float mu  = sum[f]   * (1.f / 8192.f);
    float var = sumsq[f] * (1.f / 8192.f) - mu * mu;
    float a = gamma[f] * rsqrtf(var + 1e-5f);
    a_out[f] = a;
    c_out[f] = beta[f] - mu * a;
}

// b1p[h] = b1[h] + sum_f c[f]*W1[f,h]
__global__ void fold_bias(const float* __restrict__ W1, const float* __restrict__ c,
                          const float* __restrict__ b1, int F, float* __restrict__ b1p) {
    int h = threadIdx.x & 31, g = threadIdx.x >> 5;  // 8 groups
    float s = 0.f;
    for (int f = g; f < F; f += 8) s += c[f] * W1[(size_t)f * 32 + h];
    __shared__ float red[8][32];
    red[g][h] = s;
    __syncthreads();
    if (g == 0) {
        float tot = b1[h];
        #pragma unroll
        for (int gg = 0; gg < 8; gg++) tot += red[gg][h];
        b1p[h] = tot;
    }
}

// ---------------- Subnet: x[NB,F] -> relu MLP -> hout[NB,32]  (fp32) ----------------
__global__ void subnet_kernel(const float* __restrict__ x, int F,
                              const float* __restrict__ a, const float* __restrict__ b1p,
                              const float* __restrict__ W1,
                              const float* __restrict__ W2, const float* __restrict__ b2,
                              const float* __restrict__ W3, const float* __restrict__ b3,
                              float* __restrict__ hout) {
    __shared__ float Xt[128][33];
    __shared__ float Wc[32][32];
    __shared__ float Ht[128][33];
    int t = threadIdx.x;
    int row0 = blockIdx.x * 128;
    int h = t & 31, rg = t >> 5;             // 8 groups x 16 rows

    float acc[16];
    #pragma unroll
    for (int i = 0; i < 16; i++) acc[i] = 0.f;

    for (int k0 = 0; k0 < F; k0 += 32) {
        int kc = F - k0; if (kc > 32) kc = 32;
        __syncthreads();
        if (kc == 32) {
            for (int idx = t; idx < 128 * 32; idx += 256) {
                int r = idx >> 5, kk = idx & 31;
                Xt[r][kk] = x[(size_t)(row0 + r) * F + k0 + kk];
            }
        } else {
            for (int idx = t; idx < 128 * kc; idx += 256) {
                int r = idx / kc, kk = idx - r * kc;
                Xt[r][kk] = x[(size_t)(row0 + r) * F + k0 + kk];
            }
        }
        for (int idx = t; idx < kc * 32; idx += 256) {
            int kk = idx >> 5, hh = idx & 31;
            Wc[kk][hh] = a[k0 + kk] * W1[(size_t)(k0 + kk) * 32 + hh];
        }
        __syncthreads();
        for (int kk = 0; kk < kc; kk++) {
            float w = Wc[kk][h];
            #pragma unroll
            for (int rr = 0; rr < 16; rr++)
                acc[rr] += Xt[rg * 16 + rr][kk] * w;
        }
    }
    // layer 1 activation
    {
        float b = b1p[h];
        #pragma unroll
        for (int rr = 0; rr < 16; rr++)
            Ht[rg * 16 + rr][h] = fmaxf(acc[rr] + b, 0.f);
    }
    // stage W2
    for (int idx = t; idx < 1024; idx += 256) Wc[idx >> 5][idx & 31] = W2[idx];
    __syncthreads();
    float acc2[16];
    #pragma unroll
    for (int i = 0; i < 16; i++) acc2[i] = 0.f;
    for (int q = 0; q < 32; q++) {
        float w = Wc[q][h];
        #pragma unroll
        for (int rr = 0; rr < 16; rr++) acc2[rr] += Ht[rg * 16 + rr][q] * w;
    }
    __syncthreads();
    {
        float b = b2[h];
        #pragma unroll
        for (int rr = 0; rr < 16; rr++)
            Ht[rg * 16 + rr][h] = fmaxf(acc2[rr] + b, 0.f);
    }
    for (int idx = t; idx < 1024; idx += 256) Wc[idx >> 5][idx & 31] = W3[idx];
    __syncthreads();
    float acc3[16];
    #pragma unroll
    for (int i = 0; i < 16; i++) acc3[i] = 0.f;
    for (int q = 0; q < 32; q++) {
        float w = Wc[q][h];
        #pragma unroll
        for (int rr = 0; rr < 16; rr++) acc3[rr] += Ht[rg * 16 + rr][q] * w;
    }
    {
        float b = b3[h];
        #pragma unroll
        for (int rr = 0; rr < 16; rr++)
            hout[(size_t)(row0 + rg * 16 + rr) * 32 + h] = fmaxf(acc3[rr] + b, 0.f);
    }
}

// ---------------- p1[b, k*33+i] = mk1[b,k]*us1[b,i] (bf16, K-padded) ----------------
__global__ void build_p1(const float* __restrict__ mk_h, const float* __restrict__ us_h,
                         bf16* __restrict__ p1) {
    int b = blockIdx.x;
    int t = threadIdx.x;
    __shared__ float mk1[33], us1[33];
    if (t == 0) { mk1[0] = 1.f; us1[0] = 1.f; }
    if (t < 32) mk1[t + 1] = mk_h[(size_t)b * 32 + t];
    else if (t < 64) us1[t - 31] = us_h[(size_t)b * 32 + (t - 32)];
    __syncthreads();
    for (int idx = t; idx < KP; idx += 256) {
        float v = 0.f;
        if (idx < 1089) {
            int k = idx / 33, i = idx - k * 33;
            v = mk1[k] * us1[i];
        }
        p1[(size_t)b * KP + idx] = __float2bfloat16(v);
    }
}

// ---------------- W2t[n][kk]  (bf16, transposed for B-fragment ds_read_b128) ----------------
// n = j*33+o (N axis), kk = k*33+i (K axis); W2t[n][kk] = Wf1[(k*1089 + j*33 + i)*33 + o]
__global__ void prep_w2(const float* __restrict__ Wf1, bf16* __restrict__ W2t) {
    int idx = blockIdx.x * 256 + threadIdx.x;
    if (idx >= NP * KP) return;
    int n = idx / KP, kk = idx - n * KP;
    float v = 0.f;
    if (n < 1089 && kk < 1089) {
        int j = n / 33,  o = n - j * 33;
        int k = kk / 33, i = kk - k * 33;
        v = Wf1[(size_t)(k * 1089 + j * 33 + i) * 33 + o];
    }
    W2t[idx] = __float2bfloat16(v);
}

// ---------------- Main GEMM: S[8192,1152] = p1[8192,1120] @ W2t^T  (bf16 MFMA) ----------------
__global__ void gemm_kernel(const bf16* __restrict__ A,   // [NB][KP]
                            const bf16* __restrict__ Bt,  // [NP][KP]
                            float* __restrict__ S) {      // [NB][NP]
    __shared__ __align__(16) bf16 As[128 * 40];
    __shared__ __align__(16) bf16 Bs[128 * 40];
    int t = threadIdx.x;
    int m0 = blockIdx.x * 128;
    int n0 = blockIdx.y * 128;
    int wave = t >> 6, lane = t & 63;
    int wm = (wave & 1) * 64, wn = (wave >> 1) * 64;
    int fr = lane & 15;            // row within a 16-tile
    int kg = (lane >> 4) * 8;      // k-offset of this lane's 8 elements

    f32x4 acc[4][4] = {};

    for (int k0 = 0; k0 < KP; k0 += 32) {
        __syncthreads();
        #pragma unroll
        for (int pass = 0; pass < 2; pass++) {
            int r = (t >> 2) + pass * 64;
            int ko = (t & 3) * 8;
            s16x8 av = *(const s16x8*)(A  + (size_t)(m0 + r) * KP + k0 + ko);
            *(s16x8*)(As + r * 40 + ko) = av;
            s16x8 bv = *(const s16x8*)(Bt + (size_t)(n0 + r) * KP + k0 + ko);
            *(s16x8*)(Bs + r * 40 + ko) = bv;
        }
        __syncthreads();
        s16x8 bfr[4];
        #pragma unroll
        for (int nt = 0; nt < 4; nt++)
            bfr[nt] = *(const s16x8*)(Bs + (wn + nt * 16 + fr) * 40 + kg);
        #pragma unroll
        for (int mt = 0; mt < 4; mt++) {
            s16x8 af = *(const s16x8*)(As + (wm + mt * 16 + fr) * 40 + kg);
            #pragma unroll
            for (int nt = 0; nt < 4; nt++)
                acc[mt][nt] = __builtin_amdgcn_mfma_f32_16x16x32_bf16(af, bfr[nt], acc[mt][nt], 0, 0, 0);
        }
    }
    // C/D layout: col = lane&15, row = (lane>>4)*4 + reg
    int col = lane & 15, rowg = (lane >> 4) * 4;
    #pragma unroll
    for (int mt = 0; mt < 4; mt++)
        #pragma unroll
        for (int nt = 0; nt < 4; nt++)
            #pragma unroll
            for (int r = 0; r < 4; r++) {
                int gr = m0 + wm + mt * 16 + rowg + r;
                int gc = n0 + wn + nt * 16 + col;
                S[(size_t)gr * NP + gc] = acc[mt][nt][r];
            }
}

// ---------------- Epilogue: contract j with cd1, relu, final 33x5 + sigmoid ----------------
__global__ void epilogue_kernel(const float* __restrict__ S, const float* __restrict__ cd_h,
                                const float* __restrict__ bf1, const float* __restrict__ Wf2,
                                const float* __restrict__ bf2, float* __restrict__ out) {
    int w = threadIdx.x >> 6;
    int lane = threadIdx.x & 63;
    int b = blockIdx.x * 4 + w;
    __shared__ float cdsh[4][33];
    __shared__ float hsh[4][33];
    if (lane == 0) cdsh[w][0] = 1.f;
    if (lane < 32) cdsh[w][lane + 1] = cd_h[(size_t)b * 32 + lane];
    __syncthreads();
    if (lane < 33) {
        float acc = bf1[lane];
        const float* Srow = S + (size_t)b * NP;
        #pragma unroll 3
        for (int j = 0; j < 33; j++)
            acc += cdsh[w][j] * Srow[j * 33 + lane];
        hsh[w][lane] = fmaxf(acc, 0.f);
    }
    __syncthreads();
    if (lane < 5) {
        float o = bf2[lane];
        for (int q = 0; q < 33; q++) o += hsh[w][q] * Wf2[q * 5 + lane];
        out[(size_t)b * 5 + lane] = 1.f / (1.f + expf(-o));
    }
}

extern "C" void kernel_launch(void* const* d_in, const int* in_sizes, int n_in,
                              void* d_out, int out_size, void* d_ws, size_t ws_size,
                              hipStream_t stream) {
    const float* US_x     = (const float*)d_in[0];
    const float* CDFI_x   = (const float*)d_in[1];
    const float* marker_x = (const float*)d_in[2];
    const float* us_gamma = (const float*)d_in[3];
    const float* us_beta  = (const float*)d_in[4];
    const float* us_W1    = (const float*)d_in[5];
    const float* us_b1    = (const float*)d_in[6];
    const float* us_W2    = (const float*)d_in[7];
    const float* us_b2    = (const float*)d_in[8];
    const float* us_W3    = (const float*)d_in[9];
    const float* us_b3    = (const float*)d_in[10];
    const float* cd_gamma = (const float*)d_in[11];
    const float* cd_beta  = (const float*)d_in[12];
    const float* cd_W1    = (const float*)d_in[13];
    const float* cd_b1    = (const float*)d_in[14];
    const float* cd_W2    = (const float*)d_in[15];
    const float* cd_b2    = (const float*)d_in[16];
    const float* cd_W3    = (const float*)d_in[17];
    const float* cd_b3    = (const float*)d_in[18];
    const float* mk_gamma = (const float*)d_in[19];
    const float* mk_beta  = (const float*)d_in[20];
    const float* mk_W1    = (const float*)d_in[21];
    const float* mk_b1    = (const float*)d_in[22];
    const float* mk_W2    = (const float*)d_in[23];
    const float* mk_b2    = (const float*)d_in[24];
    const float* mk_W3    = (const float*)d_in[25];
    const float* mk_b3    = (const float*)d_in[26];
    const float* Wf1      = (const float*)d_in[27];
    const float* bf1      = (const float*)d_in[28];
    const float* Wf2      = (const float*)d_in[29];
    const float* bf2      = (const float*)d_in[30];
    float* out = (float*)d_out;

    char* ws = (char*)d_ws;
    size_t off = 0;
    auto alloc = [&](size_t bytes) -> void* {
        void* p = ws + off;
        off = (off + bytes + 255) & ~(size_t)255;
        return p;
    };

    // BN stat accumulators (one contiguous region, zeroed once per call)
    float* stat_acc = (float*)alloc(4224 * sizeof(float));
    float* sum_us   = stat_acc;
    float* sumsq_us = stat_acc + 1024;
    float* sum_cd   = stat_acc + 2048;
    float* sumsq_cd = stat_acc + 3072;
    float* sum_mk   = stat_acc + 4096;
    float* sumsq_mk = stat_acc + 4160;

    float* a_us = (float*)alloc(1024 * 4); float* c_us = (float*)alloc(1024 * 4);
    float* a_cd = (float*)alloc(1024 * 4); float* c_cd = (float*)alloc(1024 * 4);
    float* a_mk = (float*)alloc(64 * 4);   float* c_mk = (float*)alloc(64 * 4);
    float* b1p_us = (float*)alloc(32 * 4);
    float* b1p_cd = (float*)alloc(32 * 4);
    float* b1p_mk = (float*)alloc(32 * 4);
    float* us_h = (float*)alloc((size_t)NB * 32 * 4);
    float* cd_h = (float*)alloc((size_t)NB * 32 * 4);
    float* mk_h = (float*)alloc((size_t)NB * 32 * 4);
    bf16*  p1   = (bf16*)alloc((size_t)NB * KP * 2);
    bf16*  W2t  = (bf16*)alloc((size_t)NP * KP * 2);
    float* S    = (float*)alloc((size_t)NB * NP * 4);

    hipMemsetAsync(stat_acc, 0, 4224 * sizeof(float), stream);

    // BN stats
    stats_partial<<<dim3(16, 32), 256, 0, stream>>>(US_x,     1024, sum_us, sumsq_us);
    stats_partial<<<dim3(16, 32), 256, 0, stream>>>(CDFI_x,   1024, sum_cd, sumsq_cd);
    stats_partial<<<dim3(1, 32),  256, 0, stream>>>(marker_x,   10, sum_mk, sumsq_mk);
    stats_finalize<<<4, 256, 0, stream>>>(sum_us, sumsq_us, us_gamma, us_beta, 1024, a_us, c_us);
    stats_finalize<<<4, 256, 0, stream>>>(sum_cd, sumsq_cd, cd_gamma, cd_beta, 1024, a_cd, c_cd);
    stats_finalize<<<1, 256, 0, stream>>>(sum_mk, sumsq_mk, mk_gamma, mk_beta,   10, a_mk, c_mk);
    fold_bias<<<1, 256, 0, stream>>>(us_W1, c_us, us_b1, 1024, b1p_us);
    fold_bias<<<1, 256, 0, stream>>>(cd_W1, c_cd, cd_b1, 1024, b1p_cd);
    fold_bias<<<1, 256, 0, stream>>>(mk_W1, c_mk, mk_b1,   10, b1p_mk);

    // Subnets (fp32, BN folded into layer 1)
    subnet_kernel<<<64, 256, 0, stream>>>(US_x,     1024, a_us, b1p_us, us_W1, us_W2, us_b2, us_W3, us_b3, us_h);
    subnet_kernel<<<64, 256, 0, stream>>>(CDFI_x,   1024, a_cd, b1p_cd, cd_W1, cd_W2, cd_b2, cd_W3, cd_b3, cd_h);
    subnet_kernel<<<64, 256, 0, stream>>>(marker_x,   10, a_mk, b1p_mk, mk_W1, mk_W2, mk_b2, mk_W3, mk_b3, mk_h);

    // GEMM operands
    build_p1<<<NB, 256, 0, stream>>>(mk_h, us_h, p1);
    prep_w2<<<(NP * KP + 255) / 256, 256, 0, stream>>>(Wf1, W2t);

    // S = p1 @ W2  (M=8192, N=1152, K=1120)
    gemm_kernel<<<dim3(NB / 128, NP / 128), 256, 0, stream>>>(p1, W2t, S);

    // cd-contraction + relu + final dense + sigmoid
    epilogue_kernel<<<NB / 4, 256, 0, stream>>>(S, cd_h, bf1, Wf2, bf2, out);
}

// Round 2
// 338.946 us; speedup vs baseline: 2.1068x; 2.1068x over previous
//
#include <hip/hip_runtime.h>
#include <hip/hip_bf16.h>
#include <math.h>

typedef __hip_bfloat16 bf16;
typedef __attribute__((ext_vector_type(4))) float f32x4;
typedef __attribute__((ext_vector_type(8))) short s16x8;

#define NB 8192
#define KP 1120   // padded K: 1089 -> 35*32
#define NP 1152   // padded N: 1089 -> 9*128

struct SubP {
    const float* x; const float* gamma; const float* beta;
    const float* W1; const float* b1; const float* W2; const float* b2;
    const float* W3; const float* b3;
    float* sum; float* sumsq; float* a; float* c; float* b1p; float* hout;
    int F;
};
struct SubP3 { SubP s[3]; };

// ---------------- BatchNorm stats (all 3 subnets, one launch) ----------------
__global__ void stats3_kernel(SubP3 P) {
    const SubP p = P.s[blockIdx.z];
    int F = p.F;
    int fl = threadIdx.x & 63;
    int rg = threadIdx.x >> 6;               // 0..3
    int f = blockIdx.x * 64 + fl;
    int rc = blockIdx.y;                     // 32 row chunks of 256
    float s = 0.f, s2 = 0.f;
    if (f < F) {
        int rend = rc * 256 + 256;
        for (int r = rc * 256 + rg; r < rend; r += 4) {
            float v = p.x[(size_t)r * F + f];
            s += v; s2 += v * v;
        }
    }
    __shared__ float l1[4][64], l2[4][64];
    l1[rg][fl] = s; l2[rg][fl] = s2;
    __syncthreads();
    if (rg == 0 && f < F) {
        float S  = l1[0][fl] + l1[1][fl] + l1[2][fl] + l1[3][fl];
        float S2 = l2[0][fl] + l2[1][fl] + l2[2][fl] + l2[3][fl];
        atomicAdd(&p.sum[f], S);
        atomicAdd(&p.sumsq[f], S2);
    }
}

__global__ void finalize3_kernel(SubP3 P) {
    const SubP p = P.s[blockIdx.y];
    int f = blockIdx.x * 256 + threadIdx.x;
    if (f >= p.F) return;
    float mu  = p.sum[f]   * (1.f / 8192.f);
    float var = p.sumsq[f] * (1.f / 8192.f) - mu * mu;
    float a = p.gamma[f] * rsqrtf(var + 1e-5f);
    p.a[f] = a;
    p.c[f] = p.beta[f] - mu * a;
}

// b1p[h] = b1[h] + sum_f c[f]*W1[f,h]
__global__ void fold3_kernel(SubP3 P) {
    const SubP p = P.s[blockIdx.x];
    int h = threadIdx.x & 31, g = threadIdx.x >> 5;  // 8 groups
    float s = 0.f;
    for (int f = g; f < p.F; f += 8) s += p.c[f] * p.W1[(size_t)f * 32 + h];
    __shared__ float red[8][32];
    red[g][h] = s;
    __syncthreads();
    if (g == 0) {
        float tot = p.b1[h];
        #pragma unroll
        for (int gg = 0; gg < 8; gg++) tot += red[gg][h];
        p.b1p[h] = tot;
    }
}

// ---------------- Subnet MLP: 32 rows/block, all 3 subnets in one launch ----------------
__global__ void __launch_bounds__(256) subnet3_kernel(SubP3 P) {
    const SubP p = P.s[blockIdx.y];
    const int F = p.F;
    __shared__ float Xt[32][132];     // 32 rows x 128-k chunk (pad to 132 for f4 alignment)
    __shared__ float Wc[128][33];     // k x h
    __shared__ float Red[4][32][33];  // wave partials / later H2
    int t = threadIdx.x;
    int row0 = blockIdx.x * 32;
    int h = t & 31, g = t >> 5;       // 8 k-groups x 32 h

    float acc[32];
    #pragma unroll
    for (int r = 0; r < 32; r++) acc[r] = 0.f;

    for (int k0 = 0; k0 < F; k0 += 128) {
        int kc = F - k0; if (kc > 128) kc = 128;
        __syncthreads();
        if (kc == 128) {
            #pragma unroll
            for (int i = 0; i < 4; i++) {
                int idx4 = t + i * 256;
                int r = idx4 >> 5, c4 = (idx4 & 31) * 4;
                float4 v = *(const float4*)&p.x[(size_t)(row0 + r) * F + k0 + c4];
                *(float4*)&Xt[r][c4] = v;
            }
        } else {
            for (int idx = t; idx < 32 * kc; idx += 256) {
                int r = idx / kc, kk = idx - r * kc;
                Xt[r][kk] = p.x[(size_t)(row0 + r) * F + k0 + kk];
            }
        }
        for (int idx = t; idx < kc * 32; idx += 256) {
            int kk = idx >> 5, hh = idx & 31;
            Wc[kk][hh] = p.a[k0 + kk] * p.W1[(size_t)(k0 + kk) * 32 + hh];
        }
        __syncthreads();
        if (kc == 128) {
            int kbase = g * 16;
            #pragma unroll
            for (int kq = 0; kq < 16; kq += 4) {
                float w0 = Wc[kbase + kq + 0][h];
                float w1 = Wc[kbase + kq + 1][h];
                float w2 = Wc[kbase + kq + 2][h];
                float w3 = Wc[kbase + kq + 3][h];
                #pragma unroll
                for (int r = 0; r < 32; r++) {
                    float4 xv = *(const float4*)&Xt[r][kbase + kq];
                    acc[r] = fmaf(xv.x, w0, fmaf(xv.y, w1, fmaf(xv.z, w2, fmaf(xv.w, w3, acc[r]))));
                }
            }
        } else {
            for (int kk = g; kk < kc; kk += 8) {
                float w = Wc[kk][h];
                #pragma unroll
                for (int r = 0; r < 32; r++)
                    acc[r] += Xt[r][kk] * w;
            }
        }
    }
    // pair-reduce g and g^1 (lanes t, t^32 within the wave)
    #pragma unroll
    for (int r = 0; r < 32; r++) acc[r] += __shfl_xor(acc[r], 32);
    int wave = t >> 6, lane = t & 63;
    if (lane < 32) {
        #pragma unroll
        for (int r = 0; r < 32; r++) Red[wave][r][lane] = acc[r];
    }
    __syncthreads();
    // H1 = relu(sum + b1p) -> store into Xt[row][h]
    {
        int rgrp = t >> 5;
        float b = p.b1p[h];
        #pragma unroll
        for (int q = 0; q < 4; q++) {
            int row = rgrp * 4 + q;
            float v = b + Red[0][row][h] + Red[1][row][h] + Red[2][row][h] + Red[3][row][h];
            Xt[row][h] = fmaxf(v, 0.f);
        }
    }
    for (int idx = t; idx < 1024; idx += 256) Wc[idx >> 5][idx & 31] = p.W2[idx];
    __syncthreads();
    // layer 2
    float* H2 = (float*)Red;
    {
        int rgrp = t >> 5;
        float a2[4] = {0.f, 0.f, 0.f, 0.f};
        for (int q = 0; q < 32; q++) {
            float w = Wc[q][h];
            #pragma unroll
            for (int i = 0; i < 4; i++) a2[i] += Xt[rgrp * 4 + i][q] * w;
        }
        float b = p.b2[h];
        #pragma unroll
        for (int i = 0; i < 4; i++)
            H2[(rgrp * 4 + i) * 33 + h] = fmaxf(a2[i] + b, 0.f);
    }
    __syncthreads();
    for (int idx = t; idx < 1024; idx += 256) Wc[idx >> 5][idx & 31] = p.W3[idx];
    __syncthreads();
    // layer 3 -> global
    {
        int rgrp = t >> 5;
        float a3[4] = {0.f, 0.f, 0.f, 0.f};
        for (int q = 0; q < 32; q++) {
            float w = Wc[q][h];
            #pragma unroll
            for (int i = 0; i < 4; i++) a3[i] += H2[(rgrp * 4 + i) * 33 + q] * w;
        }
        float b = p.b3[h];
        #pragma unroll
        for (int i = 0; i < 4; i++)
            p.hout[(size_t)(row0 + rgrp * 4 + i) * 32 + h] = fmaxf(a3[i] + b, 0.f);
    }
}

// ---------------- p1[b, k*33+i] = mk1[b,k]*us1[b,i] (bf16, K-padded) ----------------
__global__ void build_p1(const float* __restrict__ mk_h, const float* __restrict__ us_h,
                         bf16* __restrict__ p1) {
    int b = blockIdx.x;
    int t = threadIdx.x;
    __shared__ float mk1[33], us1[33];
    if (t == 0) { mk1[0] = 1.f; us1[0] = 1.f; }
    if (t < 32) mk1[t + 1] = mk_h[(size_t)b * 32 + t];
    else if (t < 64) us1[t - 31] = us_h[(size_t)b * 32 + (t - 32)];
    __syncthreads();
    if (t < 140) {
        int base = t * 8;
        s16x8 v;
        #pragma unroll
        for (int e = 0; e < 8; e++) {
            int idx = base + e;
            float val = 0.f;
            if (idx < 1089) {
                int k = idx / 33, i = idx - k * 33;
                val = mk1[k] * us1[i];
            }
            __hip_bfloat16 hb = __float2bfloat16(val);
            v[e] = *(short*)&hb;
        }
        *(s16x8*)(p1 + (size_t)b * KP + base) = v;
    }
}

// ---------------- W2t[j*33+o][k*33+i] = Wf1[k*35937 + j*1089 + i*33 + o] ----------------
__global__ void prep_w2(const float* __restrict__ Wf1, bf16* __restrict__ W2t) {
    int kj = blockIdx.x;
    int k = kj / 33, j = kj - k * 33;
    __shared__ float tile[1089];
    const float* src = Wf1 + (size_t)k * 35937 + (size_t)j * 1089;  // [i][o] contiguous
    for (int idx = threadIdx.x; idx < 1089; idx += 128) tile[idx] = src[idx];
    __syncthreads();
    for (int idx = threadIdx.x; idx < 1089; idx += 128) {
        int o = idx / 33, i = idx - o * 33;   // i inner -> coalesced writes
        W2t[(size_t)(j * 33 + o) * KP + k * 33 + i] = __float2bfloat16(tile[i * 33 + o]);
    }
}

// ---------------- Main GEMM: S[8192,1152] = p1 @ W2t^T (bf16 MFMA, m97-style) ----------------
__global__ void __launch_bounds__(256) gemm_kernel(const bf16* __restrict__ A,   // [NB][KP]
                                                   const bf16* __restrict__ Bt,  // [NP][KP]
                                                   float* __restrict__ S) {      // [NB][NP]
    __shared__ __align__(16) bf16 As[128 * 32];
    __shared__ __align__(16) bf16 Bs[128 * 32];
    int t = threadIdx.x;
    int m0 = blockIdx.x * 128;
    int n0 = blockIdx.y * 128;
    int wave = t >> 6, lane = t & 63;
    int wm = (wave & 1) * 64, wn = (wave >> 1) * 64;
    int fr = lane & 15;            // row within a 16-tile
    int kg = (lane >> 4) * 8;      // k-offset of this lane's 8 elements

    // staging: per instruction, 64 lanes x 16B = 16 rows of 32 bf16 (64B each)
    int lr = lane >> 2;            // 0..15
    int lk = (lane & 3) * 8;       // element offset 0/8/16/24
    const bf16* Ag = A  + (size_t)(m0 + wave * 32 + lr) * KP + lk;
    const bf16* Bg = Bt + (size_t)(n0 + wave * 32 + lr) * KP + lk;
    bf16* AsW = As + wave * 32 * 32;
    bf16* BsW = Bs + wave * 32 * 32;

    f32x4 acc[4][4] = {};

    for (int k0 = 0; k0 < KP; k0 += 32) {
        __syncthreads();
        __builtin_amdgcn_global_load_lds(
            (const __attribute__((address_space(1))) void*)(Ag + k0),
            (__attribute__((address_space(3))) void*)(AsW), 16, 0, 0);
        __builtin_amdgcn_global_load_lds(
            (const __attribute__((address_space(1))) void*)(Ag + k0 + 16 * KP),
            (__attribute__((address_space(3))) void*)(AsW + 16 * 32), 16, 0, 0);
        __builtin_amdgcn_global_load_lds(
            (const __attribute__((address_space(1))) void*)(Bg + k0),
            (__attribute__((address_space(3))) void*)(BsW), 16, 0, 0);
        __builtin_amdgcn_global_load_lds(
            (const __attribute__((address_space(1))) void*)(Bg + k0 + 16 * KP),
            (__attribute__((address_space(3))) void*)(BsW + 16 * 32), 16, 0, 0);
        __syncthreads();
        s16x8 bfr[4];
        #pragma unroll
        for (int nt = 0; nt < 4; nt++)
            bfr[nt] = *(const s16x8*)(Bs + (wn + nt * 16 + fr) * 32 + kg);
        #pragma unroll
        for (int mt = 0; mt < 4; mt++) {
            s16x8 af = *(const s16x8*)(As + (wm + mt * 16 + fr) * 32 + kg);
            #pragma unroll
            for (int nt = 0; nt < 4; nt++)
                acc[mt][nt] = __builtin_amdgcn_mfma_f32_16x16x32_bf16(af, bfr[nt], acc[mt][nt], 0, 0, 0);
        }
    }
    // C/D layout: col = lane&15, row = (lane>>4)*4 + reg
    int col = lane & 15, rowg = (lane >> 4) * 4;
    #pragma unroll
    for (int mt = 0; mt < 4; mt++)
        #pragma unroll
        for (int nt = 0; nt < 4; nt++)
            #pragma unroll
            for (int r = 0; r < 4; r++) {
                int gr = m0 + wm + mt * 16 + rowg + r;
                int gc = n0 + wn + nt * 16 + col;
                S[(size_t)gr * NP + gc] = acc[mt][nt][r];
            }
}

// ---------------- Epilogue: contract j with cd1, relu, final 33x5 + sigmoid ----------------
__global__ void epilogue_kernel(const float* __restrict__ S, const float* __restrict__ cd_h,
                                const float* __restrict__ bf1, const float* __restrict__ Wf2,
                                const float* __restrict__ bf2, float* __restrict__ out) {
    int w = threadIdx.x >> 6;
    int lane = threadIdx.x & 63;
    int b = blockIdx.x * 4 + w;
    __shared__ float cdsh[4][33];
    __shared__ float hsh[4][33];
    if (lane == 0) cdsh[w][0] = 1.f;
    if (lane < 32) cdsh[w][lane + 1] = cd_h[(size_t)b * 32 + lane];
    __syncthreads();
    if (lane < 33) {
        float acc = bf1[lane];
        const float* Srow = S + (size_t)b * NP;
        #pragma unroll 3
        for (int j = 0; j < 33; j++)
            acc += cdsh[w][j] * Srow[j * 33 + lane];
        hsh[w][lane] = fmaxf(acc, 0.f);
    }
    __syncthreads();
    if (lane < 5) {
        float o = bf2[lane];
        for (int q = 0; q < 33; q++) o += hsh[w][q] * Wf2[q * 5 + lane];
        out[(size_t)b * 5 + lane] = 1.f / (1.f + expf(-o));
    }
}

extern "C" void kernel_launch(void* const* d_in, const int* in_sizes, int n_in,
                              void* d_out, int out_size, void* d_ws, size_t ws_size,
                              hipStream_t stream) {
    const float* US_x     = (const float*)d_in[0];
    const float* CDFI_x   = (const float*)d_in[1];
    const float* marker_x = (const float*)d_in[2];
    const float* Wf1      = (const float*)d_in[27];
    const float* bf1      = (const float*)d_in[28];
    const float* Wf2      = (const float*)d_in[29];
    const float* bf2      = (const float*)d_in[30];
    float* out = (float*)d_out;

    char* ws = (char*)d_ws;
    size_t off = 0;
    auto alloc = [&](size_t bytes) -> void* {
        void* p = ws + off;
        off = (off + bytes + 255) & ~(size_t)255;
        return p;
    };

    float* stat_acc = (float*)alloc(4224 * sizeof(float));
    float* a_buf[3], *c_buf[3], *b1p_buf[3], *h_buf[3];
    for (int i = 0; i < 3; i++) {
        a_buf[i]   = (float*)alloc(1024 * 4);
        c_buf[i]   = (float*)alloc(1024 * 4);
        b1p_buf[i] = (float*)alloc(32 * 4);
        h_buf[i]   = (float*)alloc((size_t)NB * 32 * 4);
    }
    bf16*  p1   = (bf16*)alloc((size_t)NB * KP * 2);
    bf16*  W2t  = (bf16*)alloc((size_t)NP * KP * 2);
    float* S    = (float*)alloc((size_t)NB * NP * 4);

    SubP3 P;
    const float* xs[3] = {US_x, CDFI_x, marker_x};
    int Fs[3] = {1024, 1024, 10};
    // d_in layout: per-subnet params start at 3 (us), 11 (cd), 19 (mk):
    // gamma,beta,W1,b1,W2,b2,W3,b3
    for (int i = 0; i < 3; i++) {
        int base = 3 + i * 8;
        P.s[i].x     = xs[i];
        P.s[i].gamma = (const float*)d_in[base + 0];
        P.s[i].beta  = (const float*)d_in[base + 1];
        P.s[i].W1    = (const float*)d_in[base + 2];
        P.s[i].b1    = (const float*)d_in[base + 3];
        P.s[i].W2    = (const float*)d_in[base + 4];
        P.s[i].b2    = (const float*)d_in[base + 5];
        P.s[i].W3    = (const float*)d_in[base + 6];
        P.s[i].b3    = (const float*)d_in[base + 7];
        P.s[i].sum   = stat_acc + i * 1408;
        P.s[i].sumsq = stat_acc + i * 1408 + 704;
        P.s[i].a     = a_buf[i];
        P.s[i].c     = c_buf[i];
        P.s[i].b1p   = b1p_buf[i];
        P.s[i].hout  = h_buf[i];
        P.s[i].F     = Fs[i];
    }
    // NOTE: sum/sumsq need 1024 floats each for F=1024 — 1408*4 regions overlap!
    // Fix: give each subnet its own 2048-float region.
    // (stat_acc sized 4224 < 3*2048; re-derive properly below.)
    float* stat_big = (float*)alloc(3 * 2048 * sizeof(float));
    for (int i = 0; i < 3; i++) {
        P.s[i].sum   = stat_big + i * 2048;
        P.s[i].sumsq = stat_big + i * 2048 + 1024;
    }

    float* us_h = h_buf[0];
    float* cd_h = h_buf[1];
    float* mk_h = h_buf[2];

    hipMemsetAsync(stat_big, 0, 3 * 2048 * sizeof(float), stream);
    hipMemsetAsync(W2t, 0, (size_t)NP * KP * 2, stream);

    stats3_kernel<<<dim3(16, 32, 3), 256, 0, stream>>>(P);
    finalize3_kernel<<<dim3(4, 3), 256, 0, stream>>>(P);
    fold3_kernel<<<3, 256, 0, stream>>>(P);
    subnet3_kernel<<<dim3(256, 3), 256, 0, stream>>>(P);

    build_p1<<<NB, 192, 0, stream>>>(mk_h, us_h, p1);
    prep_w2<<<1089, 128, 0, stream>>>(Wf1, W2t);

    gemm_kernel<<<dim3(NB / 128, NP / 128), 256, 0, stream>>>(p1, W2t, S);

    epilogue_kernel<<<NB / 4, 256, 0, stream>>>(S, cd_h, bf1, Wf2, bf2, out);
}